// Round 1
// baseline (605.833 us; speedup 1.0000x reference)
//
#include <hip/hip_runtime.h>
#include <hip/hip_bf16.h>

// SparseTransE scoring:
//   ent rows [0, n_ent) are L2-normalized (norm floored at EPS) on the fly;
//   relation rows [n_ent, n_ent+n_rel) are used as-is.
//   score(h,r,t) = -sum((eh/||eh|| + er - et/||et||)^2)
// One 64-lane wave per score; lane i owns float4 elements [4i,4i+4) of each
// 256-float row -> each row read is a single coalesced 1KB dwordx4 wave load.

#define EMB 256
#define EPS 1e-12f

__device__ __forceinline__ float wave_reduce_sum(float v) {
    // butterfly across all 64 lanes
    v += __shfl_xor(v, 32, 64);
    v += __shfl_xor(v, 16, 64);
    v += __shfl_xor(v, 8, 64);
    v += __shfl_xor(v, 4, 64);
    v += __shfl_xor(v, 2, 64);
    v += __shfl_xor(v, 1, 64);
    return v;
}

__global__ __launch_bounds__(256) void transe_score_kernel(
    const float* __restrict__ emb,
    const int* __restrict__ pos_h, const int* __restrict__ pos_r, const int* __restrict__ pos_t,
    const int* __restrict__ neg_h, const int* __restrict__ neg_r, const int* __restrict__ neg_t,
    const int* __restrict__ n_ent_ptr,
    float* __restrict__ out, int B)
{
    const int wave = (blockIdx.x * blockDim.x + threadIdx.x) >> 6;
    const int lane = threadIdx.x & 63;
    const int total = 2 * B;
    if (wave >= total) return;

    const int n_ent = *n_ent_ptr;

    int h, r, t;
    if (wave < B) {
        h = pos_h[wave]; r = pos_r[wave]; t = pos_t[wave];
    } else {
        const int i = wave - B;
        h = neg_h[i]; r = neg_r[i]; t = neg_t[i];
    }

    const float4* hrow = (const float4*)(emb + (size_t)h * EMB);
    const float4* rrow = (const float4*)(emb + ((size_t)r + (size_t)n_ent) * EMB);
    const float4* trow = (const float4*)(emb + (size_t)t * EMB);

    const float4 hv = hrow[lane];
    const float4 tv = trow[lane];
    const float4 rv = rrow[lane];

    float hs = hv.x * hv.x + hv.y * hv.y + hv.z * hv.z + hv.w * hv.w;
    float ts = tv.x * tv.x + tv.y * tv.y + tv.z * tv.z + tv.w * tv.w;

    hs = wave_reduce_sum(hs);
    ts = wave_reduce_sum(ts);

    const float inh = 1.0f / fmaxf(sqrtf(hs), EPS);
    const float int_ = 1.0f / fmaxf(sqrtf(ts), EPS);

    const float vx = hv.x * inh + rv.x - tv.x * int_;
    const float vy = hv.y * inh + rv.y - tv.y * int_;
    const float vz = hv.z * inh + rv.z - tv.z * int_;
    const float vw = hv.w * inh + rv.w - tv.w * int_;

    float s = vx * vx + vy * vy + vz * vz + vw * vw;
    s = wave_reduce_sum(s);

    if (lane == 0) out[wave] = -s;
}

extern "C" void kernel_launch(void* const* d_in, const int* in_sizes, int n_in,
                              void* d_out, int out_size, void* d_ws, size_t ws_size,
                              hipStream_t stream) {
    const float* emb  = (const float*)d_in[0];
    const int* pos_h  = (const int*)d_in[1];
    const int* pos_r  = (const int*)d_in[2];
    const int* pos_t  = (const int*)d_in[3];
    const int* neg_h  = (const int*)d_in[4];
    const int* neg_r  = (const int*)d_in[5];
    const int* neg_t  = (const int*)d_in[6];
    const int* n_ent  = (const int*)d_in[7];
    float* out = (float*)d_out;

    const int B = in_sizes[1];          // 65536
    const int total_waves = 2 * B;      // one wave per score
    const int block = 256;              // 4 waves/block
    const int grid = (total_waves * 64 + block - 1) / block;

    transe_score_kernel<<<grid, block, 0, stream>>>(
        emb, pos_h, pos_r, pos_t, neg_h, neg_r, neg_t, n_ent, out, B);
}

// Round 2
// 602.469 us; speedup vs baseline: 1.0056x; 1.0056x over previous
//
#include <hip/hip_runtime.h>

// SparseTransE scoring:
//   ent rows [0, n_ent) are L2-normalized (norm floored at EPS) on the fly;
//   relation rows [n_ent, n_ent+n_rel) are used as-is.
//   score(h,r,t) = -sum((eh/||eh|| + er - et/||et||)^2)
//
// R1: 4 scores per wave (SPW=4) for memory-level parallelism — 12 independent
// 1KB row loads in flight per wave instead of 3; one int4 broadcast per index
// table instead of 3 scalar loads; interleaved butterfly reductions (8 values
// through the 6 shfl stages); coalesced float4 output store by lane 0.
// B=65536 is a multiple of SPW, so each wave's 4 scores are all-pos or all-neg
// (wave-uniform branch) and the out store is 16B-aligned.

#define EMB 256
#define EPS 1e-12f
#define SPW 4

__global__ __launch_bounds__(256) void transe_score_kernel(
    const float* __restrict__ emb,
    const int* __restrict__ pos_h, const int* __restrict__ pos_r, const int* __restrict__ pos_t,
    const int* __restrict__ neg_h, const int* __restrict__ neg_r, const int* __restrict__ neg_t,
    const int* __restrict__ n_ent_ptr,
    float* __restrict__ out, int B)
{
    const int wave = (blockIdx.x * blockDim.x + threadIdx.x) >> 6;
    const int lane = threadIdx.x & 63;
    const int base = wave * SPW;
    if (base >= 2 * B) return;

    const int n_ent = *n_ent_ptr;

    const int* __restrict__ hsrc;
    const int* __restrict__ rsrc;
    const int* __restrict__ tsrc;
    int off;
    if (base < B) { hsrc = pos_h; rsrc = pos_r; tsrc = pos_t; off = base; }
    else          { hsrc = neg_h; rsrc = neg_r; tsrc = neg_t; off = base - B; }

    const int4 hh = *(const int4*)(hsrc + off);
    const int4 rr = *(const int4*)(rsrc + off);
    const int4 tt = *(const int4*)(tsrc + off);

    const int hi[SPW] = {hh.x, hh.y, hh.z, hh.w};
    const int ri[SPW] = {rr.x, rr.y, rr.z, rr.w};
    const int ti[SPW] = {tt.x, tt.y, tt.z, tt.w};

    // Issue all 12 row loads before any use — compiler keeps them in flight.
    float4 hv[SPW], tv[SPW], rv[SPW];
#pragma unroll
    for (int s = 0; s < SPW; ++s) {
        hv[s] = ((const float4*)(emb + (size_t)hi[s] * EMB))[lane];
        tv[s] = ((const float4*)(emb + (size_t)ti[s] * EMB))[lane];
        rv[s] = ((const float4*)(emb + ((size_t)ri[s] + (size_t)n_ent) * EMB))[lane];
    }

    // Per-lane partial |h|^2, |t|^2 for all 4 scores, then one interleaved
    // 6-stage butterfly over 8 values (hides shfl latency with ILP).
    float red[2 * SPW];
#pragma unroll
    for (int s = 0; s < SPW; ++s) {
        red[s]       = hv[s].x * hv[s].x + hv[s].y * hv[s].y + hv[s].z * hv[s].z + hv[s].w * hv[s].w;
        red[SPW + s] = tv[s].x * tv[s].x + tv[s].y * tv[s].y + tv[s].z * tv[s].z + tv[s].w * tv[s].w;
    }
#pragma unroll
    for (int d = 32; d >= 1; d >>= 1) {
#pragma unroll
        for (int k = 0; k < 2 * SPW; ++k)
            red[k] += __shfl_xor(red[k], d, 64);
    }

    float sq[SPW];
#pragma unroll
    for (int s = 0; s < SPW; ++s) {
        const float inh = 1.0f / fmaxf(sqrtf(red[s]), EPS);
        const float itn = 1.0f / fmaxf(sqrtf(red[SPW + s]), EPS);
        const float vx = hv[s].x * inh + rv[s].x - tv[s].x * itn;
        const float vy = hv[s].y * inh + rv[s].y - tv[s].y * itn;
        const float vz = hv[s].z * inh + rv[s].z - tv[s].z * itn;
        const float vw = hv[s].w * inh + rv[s].w - tv[s].w * itn;
        sq[s] = vx * vx + vy * vy + vz * vz + vw * vw;
    }
#pragma unroll
    for (int d = 32; d >= 1; d >>= 1) {
#pragma unroll
        for (int k = 0; k < SPW; ++k)
            sq[k] += __shfl_xor(sq[k], d, 64);
    }

    if (lane == 0)
        *(float4*)(out + base) = make_float4(-sq[0], -sq[1], -sq[2], -sq[3]);
}

extern "C" void kernel_launch(void* const* d_in, const int* in_sizes, int n_in,
                              void* d_out, int out_size, void* d_ws, size_t ws_size,
                              hipStream_t stream) {
    const float* emb  = (const float*)d_in[0];
    const int* pos_h  = (const int*)d_in[1];
    const int* pos_r  = (const int*)d_in[2];
    const int* pos_t  = (const int*)d_in[3];
    const int* neg_h  = (const int*)d_in[4];
    const int* neg_r  = (const int*)d_in[5];
    const int* neg_t  = (const int*)d_in[6];
    const int* n_ent  = (const int*)d_in[7];
    float* out = (float*)d_out;

    const int B = in_sizes[1];               // 65536
    const int total = 2 * B;                 // 131072 scores
    const int waves = (total + SPW - 1) / SPW;
    const int block = 256;                   // 4 waves/block
    const int grid = (waves * 64 + block - 1) / block;

    transe_score_kernel<<<grid, block, 0, stream>>>(
        emb, pos_h, pos_r, pos_t, neg_h, neg_r, neg_t, n_ent, out, B);
}